// Round 1
// baseline (792.735 us; speedup 1.0000x reference)
//
#include <hip/hip_runtime.h>
#include <hip/hip_bf16.h>
#include <math.h>

// MultiHeadAttention with GELU-instead-of-softmax.
// x:(2,2048,1024) fp32; Wq/Wk/Wv/Wo:(1024,1024); b*:(1024,)
// out = (ctx @ Wo.T + bo)  [2,2048,1024]  +  weights = gelu(QK^T/8) [2,16,2048,2048]
// d_out = out flat (4194304 f32) ++ weights flat (134217728 f32)

using bf16 = __bf16;
typedef __bf16 bf16x8 __attribute__((ext_vector_type(8)));
typedef float  floatx4 __attribute__((ext_vector_type(4)));

#define NTOK 4096      // 2*2048 tokens
#define EMB  1024
#define SEQ  2048
#define NH   16
#define HD   64

// ---------------------------------------------------------------------------
// Kernel 1: QKV projection. C = x @ W.T + b, M=4096 N=1024 K=1024.
// z=0 -> Q (scaled 1/8) [b,h,n,d] bf16 ; z=1 -> K [b,h,n,d] ; z=2 -> V^T [b,h,d,n]
// ---------------------------------------------------------------------------
__global__ __launch_bounds__(256) void proj_qkv(
    const float* __restrict__ x,
    const float* __restrict__ Wq, const float* __restrict__ bq,
    const float* __restrict__ Wk, const float* __restrict__ bk,
    const float* __restrict__ Wv, const float* __restrict__ bv,
    bf16* __restrict__ qb, bf16* __restrict__ kb, bf16* __restrict__ vtb)
{
    const int z = blockIdx.z;
    const float* __restrict__ W    = (z == 0) ? Wq : (z == 1) ? Wk : Wv;
    const float* __restrict__ bias = (z == 0) ? bq : (z == 1) ? bk : bv;

    constexpr int BM = 128, BN = 128, BK = 64, SROW = BK + 8; // 72 elems = 144B rows (16B aligned)
    __shared__ bf16 As[BM * SROW];
    __shared__ bf16 Bs[BN * SROW];

    const int m0 = blockIdx.y * BM;
    const int n0 = blockIdx.x * BN;
    const int tid  = threadIdx.x;
    const int wave = tid >> 6, lane = tid & 63;
    const int quad = lane >> 4, r16 = lane & 15;
    const int wm = (wave >> 1) * 64, wn = (wave & 1) * 64;

    floatx4 acc[4][4];
    for (int i = 0; i < 4; i++)
        for (int j = 0; j < 4; j++)
            acc[i][j] = floatx4{0.f, 0.f, 0.f, 0.f};

    for (int k0 = 0; k0 < EMB; k0 += BK) {
        // stage A (x tile, fp32 -> bf16): 128x64 = 2048 float4, 8 per thread
        for (int i = 0; i < 8; i++) {
            int f = tid + i * 256;
            int row = f >> 4, c4 = (f & 15) * 4;
            const float4 v = *(const float4*)(x + (size_t)(m0 + row) * EMB + k0 + c4);
            bf16* dst = As + row * SROW + c4;
            dst[0] = (bf16)v.x; dst[1] = (bf16)v.y; dst[2] = (bf16)v.z; dst[3] = (bf16)v.w;
        }
        // stage B (W tile rows = output cols)
        for (int i = 0; i < 8; i++) {
            int f = tid + i * 256;
            int row = f >> 4, c4 = (f & 15) * 4;
            const float4 v = *(const float4*)(W + (size_t)(n0 + row) * EMB + k0 + c4);
            bf16* dst = Bs + row * SROW + c4;
            dst[0] = (bf16)v.x; dst[1] = (bf16)v.y; dst[2] = (bf16)v.z; dst[3] = (bf16)v.w;
        }
        __syncthreads();
        for (int ks = 0; ks < 2; ks++) {
            bf16x8 af[4], bfr[4];
            for (int t = 0; t < 4; t++)
                af[t]  = *(const bf16x8*)(As + (wm + t * 16 + r16) * SROW + ks * 32 + quad * 8);
            for (int t = 0; t < 4; t++)
                bfr[t] = *(const bf16x8*)(Bs + (wn + t * 16 + r16) * SROW + ks * 32 + quad * 8);
            for (int mt = 0; mt < 4; mt++)
                for (int nt = 0; nt < 4; nt++)
                    acc[mt][nt] = __builtin_amdgcn_mfma_f32_16x16x32_bf16(
                        af[mt], bfr[nt], acc[mt][nt], 0, 0, 0);
        }
        __syncthreads();
    }

    // epilogue: +bias, cast, scatter per layout
    for (int mt = 0; mt < 4; mt++)
        for (int nt = 0; nt < 4; nt++)
            for (int i = 0; i < 4; i++) {
                int row = m0 + wm + mt * 16 + quad * 4 + i;   // token 0..4095
                int col = n0 + wn + nt * 16 + r16;            // emb 0..1023
                float v = acc[mt][nt][i] + bias[col];
                int b = row >> 11, n = row & 2047;
                int h = col >> 6,  d = col & 63;
                if (z == 0) {
                    qb[(((size_t)(b * NH + h) * SEQ + n) << 6) + d] = (bf16)(v * 0.125f);
                } else if (z == 1) {
                    kb[(((size_t)(b * NH + h) * SEQ + n) << 6) + d] = (bf16)v;
                } else {
                    vtb[((size_t)((b * NH + h) * HD + d) << 11) + n] = (bf16)v;
                }
            }
}

// ---------------------------------------------------------------------------
// Kernel 2: attention. Per (b,h) and 128-row query tile:
//   loop over 64-wide key tiles: S = Q.K^T (Q pre-scaled), gelu -> weights out,
//   P via LDS -> ctx += P.V  (V stored transposed so PV is also bt-form)
// ---------------------------------------------------------------------------
__global__ __launch_bounds__(256) void attn(
    const bf16* __restrict__ qb, const bf16* __restrict__ kb,
    const bf16* __restrict__ vtb,
    float* __restrict__ wout,     // [32][2048][2048]
    bf16* __restrict__ ctxb)      // [4096][1024]
{
    constexpr int BM = 128, BN = 64, SQ = 72, SP = 72;
    __shared__ bf16 Qs[BM * SQ];    // 18432 B
    __shared__ bf16 Ks[BN * SQ];    //  9216 B
    __shared__ bf16 Vts[HD * SP];   //  9216 B
    __shared__ bf16 Ps[BM * SP];    // 18432 B   (total 55296 B)

    const int bh = blockIdx.y;               // b*16+h
    const int m0 = blockIdx.x * BM;          // query tile base
    const int tid  = threadIdx.x;
    const int wave = tid >> 6, lane = tid & 63;
    const int quad = lane >> 4, r16 = lane & 15;
    const int wm = (wave >> 1) * 64, wn = (wave & 1) * 32;

    const bf16* __restrict__ Q  = qb  + (size_t)bh * SEQ * HD;
    const bf16* __restrict__ K  = kb  + (size_t)bh * SEQ * HD;
    const bf16* __restrict__ Vt = vtb + (size_t)bh * HD * SEQ;
    float* __restrict__ wrow = wout + (size_t)bh * SEQ * SEQ;

    // load Q tile (128x64 bf16 = 1024 x 16B)
    for (int i = 0; i < 4; i++) {
        int f = tid + i * 256;
        int row = f >> 3, c8 = (f & 7) * 8;
        *(uint4*)(Qs + row * SQ + c8) = *(const uint4*)(Q + (size_t)(m0 + row) * HD + c8);
    }

    floatx4 ctx[4][2];
    for (int i = 0; i < 4; i++)
        for (int j = 0; j < 2; j++)
            ctx[i][j] = floatx4{0.f, 0.f, 0.f, 0.f};

    __syncthreads();

    for (int nn0 = 0; nn0 < SEQ; nn0 += BN) {
        // stage K tile (64x64) and Vt tile (64x64): 512 x16B each, 2/thread
        for (int i = 0; i < 2; i++) {
            int f = tid + i * 256;
            int row = f >> 3, c8 = (f & 7) * 8;
            *(uint4*)(Ks + row * SQ + c8) = *(const uint4*)(K + (size_t)(nn0 + row) * HD + c8);
        }
        for (int i = 0; i < 2; i++) {
            int f = tid + i * 256;
            int row = f >> 3, c8 = (f & 7) * 8;        // row = d, c8 = n-offset
            *(uint4*)(Vts + row * SP + c8) = *(const uint4*)(Vt + (size_t)row * SEQ + nn0 + c8);
        }
        __syncthreads();

        // S tile: each wave 64x32 (4x2 MFMA tiles), K-dim 64
        floatx4 s[4][2];
        for (int i = 0; i < 4; i++)
            for (int j = 0; j < 2; j++)
                s[i][j] = floatx4{0.f, 0.f, 0.f, 0.f};
        for (int ks = 0; ks < 2; ks++) {
            bf16x8 af[4], bfr[2];
            for (int t = 0; t < 4; t++)
                af[t]  = *(const bf16x8*)(Qs + (wm + t * 16 + r16) * SQ + ks * 32 + quad * 8);
            for (int t = 0; t < 2; t++)
                bfr[t] = *(const bf16x8*)(Ks + (wn + t * 16 + r16) * SQ + ks * 32 + quad * 8);
            for (int mt = 0; mt < 4; mt++)
                for (int nt = 0; nt < 2; nt++)
                    s[mt][nt] = __builtin_amdgcn_mfma_f32_16x16x32_bf16(
                        af[mt], bfr[nt], s[mt][nt], 0, 0, 0);
        }

        // gelu (exact), write weights (fp32) + P (bf16 to LDS)
        for (int mt = 0; mt < 4; mt++)
            for (int nt = 0; nt < 2; nt++)
                for (int i = 0; i < 4; i++) {
                    int row = wm + mt * 16 + quad * 4 + i;
                    int col = wn + nt * 16 + r16;
                    float sv = s[mt][nt][i];
                    float g = 0.5f * sv * (1.0f + erff(sv * 0.70710678118f));
                    wrow[(size_t)(m0 + row) * SEQ + nn0 + col] = g;
                    Ps[row * SP + col] = (bf16)g;
                }
        __syncthreads();   // Ps ready

        // ctx += P @ V : A = Ps[m][kn], B = Vts[d][kn] (bt form), K-dim 64
        for (int ks = 0; ks < 2; ks++) {
            bf16x8 af[4], bfr[2];
            for (int t = 0; t < 4; t++)
                af[t]  = *(const bf16x8*)(Ps  + (wm + t * 16 + r16) * SP + ks * 32 + quad * 8);
            for (int t = 0; t < 2; t++)
                bfr[t] = *(const bf16x8*)(Vts + (wn + t * 16 + r16) * SP + ks * 32 + quad * 8);
            for (int mt = 0; mt < 4; mt++)
                for (int nt = 0; nt < 2; nt++)
                    ctx[mt][nt] = __builtin_amdgcn_mfma_f32_16x16x32_bf16(
                        af[mt], bfr[nt], ctx[mt][nt], 0, 0, 0);
        }
        __syncthreads();   // before next iteration overwrites Ks/Vts/Ps
    }

    // epilogue: ctx -> ctxb bf16 at [b*2048+n][h*64+d]
    const int b = bh >> 4, h = bh & 15;
    for (int mt = 0; mt < 4; mt++)
        for (int nt = 0; nt < 2; nt++)
            for (int i = 0; i < 4; i++) {
                int row = m0 + wm + mt * 16 + quad * 4 + i;   // token in [0,2048)
                int d   = wn + nt * 16 + r16;
                ctxb[(size_t)(b * SEQ + row) * EMB + h * HD + d] = (bf16)ctx[mt][nt][i];
            }
}

// ---------------------------------------------------------------------------
// Kernel 3: out = ctx @ Wo.T + bo, M=4096 N=1024 K=1024, A already bf16.
// ---------------------------------------------------------------------------
__global__ __launch_bounds__(256) void outproj(
    const bf16* __restrict__ ctxb, const float* __restrict__ Wo,
    const float* __restrict__ bo, float* __restrict__ out)
{
    constexpr int BM = 128, BN = 128, BK = 64, SROW = BK + 8;
    __shared__ bf16 As[BM * SROW];
    __shared__ bf16 Bs[BN * SROW];

    const int m0 = blockIdx.y * BM;
    const int n0 = blockIdx.x * BN;
    const int tid  = threadIdx.x;
    const int wave = tid >> 6, lane = tid & 63;
    const int quad = lane >> 4, r16 = lane & 15;
    const int wm = (wave >> 1) * 64, wn = (wave & 1) * 64;

    floatx4 acc[4][4];
    for (int i = 0; i < 4; i++)
        for (int j = 0; j < 4; j++)
            acc[i][j] = floatx4{0.f, 0.f, 0.f, 0.f};

    for (int k0 = 0; k0 < EMB; k0 += BK) {
        // stage A (bf16 source): 128x64 bf16 = 1024 x16B, 4/thread
        for (int i = 0; i < 4; i++) {
            int f = tid + i * 256;
            int row = f >> 3, c8 = (f & 7) * 8;
            *(uint4*)(As + row * SROW + c8) =
                *(const uint4*)(ctxb + (size_t)(m0 + row) * EMB + k0 + c8);
        }
        // stage B (Wo fp32 -> bf16)
        for (int i = 0; i < 8; i++) {
            int f = tid + i * 256;
            int row = f >> 4, c4 = (f & 15) * 4;
            const float4 v = *(const float4*)(Wo + (size_t)(n0 + row) * EMB + k0 + c4);
            bf16* dst = Bs + row * SROW + c4;
            dst[0] = (bf16)v.x; dst[1] = (bf16)v.y; dst[2] = (bf16)v.z; dst[3] = (bf16)v.w;
        }
        __syncthreads();
        for (int ks = 0; ks < 2; ks++) {
            bf16x8 af[4], bfr[4];
            for (int t = 0; t < 4; t++)
                af[t]  = *(const bf16x8*)(As + (wm + t * 16 + r16) * SROW + ks * 32 + quad * 8);
            for (int t = 0; t < 4; t++)
                bfr[t] = *(const bf16x8*)(Bs + (wn + t * 16 + r16) * SROW + ks * 32 + quad * 8);
            for (int mt = 0; mt < 4; mt++)
                for (int nt = 0; nt < 4; nt++)
                    acc[mt][nt] = __builtin_amdgcn_mfma_f32_16x16x32_bf16(
                        af[mt], bfr[nt], acc[mt][nt], 0, 0, 0);
        }
        __syncthreads();
    }

    for (int mt = 0; mt < 4; mt++)
        for (int nt = 0; nt < 4; nt++)
            for (int i = 0; i < 4; i++) {
                int row = m0 + wm + mt * 16 + quad * 4 + i;
                int col = n0 + wn + nt * 16 + r16;
                out[(size_t)row * EMB + col] = acc[mt][nt][i] + bo[col];
            }
}

// ---------------------------------------------------------------------------
extern "C" void kernel_launch(void* const* d_in, const int* in_sizes, int n_in,
                              void* d_out, int out_size, void* d_ws, size_t ws_size,
                              hipStream_t stream) {
    const float* x  = (const float*)d_in[0];
    const float* Wq = (const float*)d_in[1];
    const float* bq = (const float*)d_in[2];
    const float* Wk = (const float*)d_in[3];
    const float* bk = (const float*)d_in[4];
    const float* Wv = (const float*)d_in[5];
    const float* bv = (const float*)d_in[6];
    const float* Wo = (const float*)d_in[7];
    const float* bo = (const float*)d_in[8];

    float* out  = (float*)d_out;
    float* wout = out + (size_t)NTOK * EMB;   // weights start after out

    bf16* qb   = (bf16*)d_ws;                 //  8 MB
    bf16* kb   = qb  + (size_t)NTOK * EMB / 4 * 4; // 4194304 elems
    bf16* vtb  = kb  + (size_t)4194304;
    bf16* ctxb = vtb + (size_t)4194304;       // total 32 MB

    proj_qkv<<<dim3(8, 32, 3), 256, 0, stream>>>(x, Wq, bq, Wk, bk, Wv, bv, qb, kb, vtb);
    attn<<<dim3(16, 32), 256, 0, stream>>>(qb, kb, vtb, wout, ctxb);
    outproj<<<dim3(8, 32), 256, 0, stream>>>(ctxb, Wo, bo, out);
}